// Round 11
// baseline (1630.943 us; speedup 1.0000x reference)
//
#include <hip/hip_runtime.h>

#define NA_N 50000
#define NB_N 50000
#define NE   1000000
#define DF   128
#define NG_N 64
#define NC_N 10

// bucketed counting sort params
#define BSHIFT 7
#define BNODES 128
#define NBUK   391
#define CHB    4096
#define NIT    (CHB / 256)
#define BINBLK ((NE + CHB - 1) / CHB)    // 245
#define AGGBLK ((NA_N * 64) / 256)       // 12500 blocks per aggregation job

#define CN4A (NA_N * DF / 4)
#define CN4T ((NA_N + NB_N) * DF / 4)
#define WELEMS (8 * 16384)
#define PZ4 (NG_N * DF / 4)
#define PREP_ITEMS (CN4T + WELEMS + PZ4 + NA_N)
#define PREP_BLKS ((PREP_ITEMS + 255) / 256)

typedef __attribute__((ext_vector_type(8))) short short8;
typedef __attribute__((ext_vector_type(4))) float float4v;
typedef __attribute__((ext_vector_type(2))) float v2f;

__device__ __forceinline__ unsigned short f2bf(float f) {
    unsigned u = __float_as_uint(f);
    unsigned r = (u + 0x7fff + ((u >> 16) & 1)) >> 16;   // RNE
    return (unsigned short)r;
}
__device__ __forceinline__ float bf_lo(unsigned d) { return __uint_as_float(d << 16); }
__device__ __forceinline__ float bf_hi(unsigned d) { return __uint_as_float(d & 0xffff0000u); }
__device__ __forceinline__ v2f bfpair(unsigned d) { return (v2f){bf_lo(d), bf_hi(d)}; }
__device__ __forceinline__ unsigned packbf(float lo, float hi) {
    return (unsigned)f2bf(lo) | ((unsigned)f2bf(hi) << 16);
}

struct WJobs {
    const float* a[8];
    const float* b[8];
    unsigned short* d[8];
};

struct CsrJobs {
    const int* src[3];
    const int* dst[3];
    int* offs[3];
    int* ss[3];
    unsigned* ebuf[3];
};

// ---------------- prep (convert + weights + pooled zero + graph bounds) + hist + scan ----------------
// Last-block ticket: the final block to finish also performs the 3 bucket scans,
// eliminating the separate 3-block scan launch (serial bubble + launch overhead).

__global__ __launch_bounds__(256) void prep_hist_k(
        const float* __restrict__ xa, const float* __restrict__ xb,
        unsigned short* __restrict__ ya, unsigned short* __restrict__ yb,
        WJobs WJ, float* __restrict__ pooled,
        const int* __restrict__ batch, int* __restrict__ bound,
        CsrJobs CJ, int* __restrict__ bcnt3,
        int* __restrict__ bbase3, int* __restrict__ bcur3, int* __restrict__ tk) {
    if ((int)blockIdx.x < PREP_BLKS) {
        int i = blockIdx.x * 256 + threadIdx.x;
        if (i < CN4T) {
            const float* x = (i < CN4A) ? xa : xb;
            unsigned short* y = (i < CN4A) ? ya : yb;
            int j = (i < CN4A) ? i : i - CN4A;
            float4 v = ((const float4*)x)[j];
            uint2 o;
            o.x = packbf(v.x, v.y);
            o.y = packbf(v.z, v.w);
            ((uint2*)y)[j] = o;
        } else if (i < CN4T + WELEMS) {
            int t = i - CN4T;
            int which = t >> 14;
            t &= 16383;
            int j = t & 7, lane = (t >> 3) & 63, k0i = (t >> 9) & 3, n0 = t >> 11;
            int k = k0i * 32 + (lane >> 4) * 8 + j;
            int n = n0 * 16 + (lane & 15);
            float v = WJ.a[which][k * DF + n];
            if (WJ.b[which]) v += WJ.b[which][k * DF + n];
            WJ.d[which][t] = f2bf(v);
        } else if (i < CN4T + WELEMS + PZ4) {
            int t = i - CN4T - WELEMS;
            ((float4*)pooled)[t] = (float4){0.f, 0.f, 0.f, 0.f};
        } else if (i < PREP_ITEMS) {
            // graph boundary precompute over sorted batch
            int rr = i - (CN4T + WELEMS + PZ4);
            int c = batch[rr];
            if (rr == 0) {
                for (int g = 0; g <= c; g++) bound[g] = 0;
            } else {
                int p = batch[rr - 1];
                for (int g = p + 1; g <= c; g++) bound[g] = rr;
            }
            if (rr == NA_N - 1) {
                for (int g = c + 1; g <= NG_N; g++) bound[g] = NA_N;
            }
        }
    } else {
        // bucket histogram part
        int hb = blockIdx.x - PREP_BLKS;
        int which = hb / BINBLK;
        int blk = hb % BINBLK;
        const int* dst = CJ.dst[which];
        int* bcnt = bcnt3 + which * NBUK;
        __shared__ int h[NBUK];
        for (int i = threadIdx.x; i < NBUK; i += 256) h[i] = 0;
        __syncthreads();
        int base = blk * CHB;
#pragma unroll
        for (int it = 0; it < NIT; it++) {
            int i = base + it * 256 + threadIdx.x;
            if (i < NE) atomicAdd(&h[dst[i] >> BSHIFT], 1);
        }
        __syncthreads();
        for (int i = threadIdx.x; i < NBUK; i += 256)
            if (h[i]) atomicAdd(&bcnt[i], h[i]);
    }
    // ---- last-block ticket -> inline bucket scans ----
    __threadfence();
    __shared__ int lastf;
    if (threadIdx.x == 0)
        lastf = (atomicAdd(&tk[0], 1) == (int)gridDim.x - 1) ? 1 : 0;
    __syncthreads();
    if (lastf && threadIdx.x < 64) {
        __threadfence();
        int lane = threadIdx.x;
        for (int j = 0; j < 3; j++) {
            const int* bcnt = bcnt3 + j * NBUK;
            int* bbase = bbase3 + j * (NBUK + 1);
            int* bcur = bcur3 + j * NBUK;
            int pre[7];
            int csum = 0;
            int base_i = lane * 7;
#pragma unroll
            for (int q = 0; q < 7; q++) {
                int ii = base_i + q;
                int v = (ii < NBUK) ? bcnt[ii] : 0;
                pre[q] = csum;
                csum += v;
            }
            int inc = csum;
            for (int d = 1; d < 64; d <<= 1) {
                int x = __shfl_up(inc, d, 64);
                if (lane >= d) inc += x;
            }
            int excl = inc - csum;
#pragma unroll
            for (int q = 0; q < 7; q++) {
                int ii = base_i + q;
                if (ii < NBUK) {
                    int e = excl + pre[q];
                    bbase[ii] = e;
                    bcur[ii] = e;
                }
            }
            if (lane == 0) bbase[NBUK] = NE;
        }
    }
}

// ---------------- CSR build (bin / sort) ----------------

__global__ __launch_bounds__(256) void bucket_bin3_k(CsrJobs J, int* __restrict__ bcur3) {
    int which = blockIdx.x / BINBLK;
    int blk = blockIdx.x % BINBLK;
    const int* src = J.src[which];
    const int* dst = J.dst[which];
    int* bcur = bcur3 + which * NBUK;
    unsigned* ebuf = J.ebuf[which];
    __shared__ int cnt[NBUK];
    __shared__ int chunk[NBUK];
    for (int i = threadIdx.x; i < NBUK; i += 256) cnt[i] = 0;
    __syncthreads();
    int base = blk * CHB;
    int bk[NIT], rk[NIT];
    unsigned sv[NIT];
#pragma unroll
    for (int it = 0; it < NIT; it++) {
        int i = base + it * 256 + threadIdx.x;
        if (i < NE) {
            int d = dst[i];
            int b = d >> BSHIFT;
            bk[it] = b;
            rk[it] = atomicAdd(&cnt[b], 1);
            sv[it] = (unsigned)src[i] | ((unsigned)(d & (BNODES - 1)) << 24);
        } else {
            bk[it] = -1;
        }
    }
    __syncthreads();
    for (int i = threadIdx.x; i < NBUK; i += 256)
        chunk[i] = cnt[i] ? atomicAdd(&bcur[i], cnt[i]) : 0;
    __syncthreads();
#pragma unroll
    for (int it = 0; it < NIT; it++)
        if (bk[it] >= 0) ebuf[chunk[bk[it]] + rk[it]] = sv[it];
}

__global__ __launch_bounds__(256) void bucket_sort3_k(CsrJobs J, const int* __restrict__ bbase3,
                                                      int ndst) {
    __shared__ int hist[BNODES];
    __shared__ int loffs[BNODES];
    int which = blockIdx.x / NBUK;
    int b = blockIdx.x % NBUK;
    const unsigned* ebuf = J.ebuf[which];
    const int* bbase = bbase3 + which * (NBUK + 1);
    int* offs = J.offs[which];
    int* ss = J.ss[which];
    int t = threadIdx.x;
    int ebase = bbase[b], ecnt = bbase[b + 1] - ebase;
    if (t < BNODES) hist[t] = 0;
    __syncthreads();
    for (int e = t; e < ecnt; e += 256)
        atomicAdd(&hist[ebuf[ebase + e] >> 24], 1);
    __syncthreads();
    if (t < BNODES) loffs[t] = hist[t];
    __syncthreads();
    for (int d = 1; d < BNODES; d <<= 1) {
        int x = 0;
        if (t < BNODES && t >= d) x = loffs[t - d];
        __syncthreads();
        if (t < BNODES && t >= d) loffs[t] += x;
        __syncthreads();
    }
    if (t < BNODES) {
        int ex = loffs[t] - hist[t];
        loffs[t] = ex;
        int gnode = b * BNODES + t;
        if (gnode < ndst) offs[gnode] = ebase + ex;
        hist[t] = 0;
    }
    if (b == 0 && t == 0) offs[ndst] = NE;
    __syncthreads();
    for (int e = t; e < ecnt; e += 256) {
        unsigned w = ebuf[ebase + e];
        int dl = w >> 24;
        int r = atomicAdd(&hist[dl], 1);
        ss[ebase + loffs[dl] + r] = (int)(w & 0xFFFFFF);
    }
}

// ---------------- segment mean (unchanged from R10: at its structural floor) ----------------

struct AggJobs {
    const unsigned short* xs[3];
    const int* offs[3];
    const int* ss[3];
    unsigned short* mean[3];
};

__device__ __forceinline__ void acc_u4(uint4 u, v2f acc[4]) {
    acc[0] += bfpair(u.x);
    acc[1] += bfpair(u.y);
    acc[2] += bfpair(u.z);
    acc[3] += bfpair(u.w);
}

__global__ __launch_bounds__(256) void aggregate_multi_k(AggJobs J) {
    int job = blockIdx.x / AGGBLK;
    int blk = blockIdx.x % AGGBLK;
    int node = (blk * 256 + threadIdx.x) >> 6;
    int lane = threadIdx.x & 63;
    const unsigned* xs = (const unsigned*)J.xs[job];
    const int* offs = J.offs[job];
    const int* ss = J.ss[job];
    int o0 = offs[node], o1 = offs[node + 1];
    int deg = o1 - o0;
    int idx = (lane < deg) ? ss[o0 + lane] : 0;
    int sub = lane >> 4;
    int q4 = (lane & 15) * 4;
    const unsigned* xq = xs + q4;
    v2f acc[4];
#pragma unroll
    for (int k = 0; k < 4; k++) acc[k] = (v2f){0.f, 0.f};

    int dcap = deg < 64 ? deg : 64;
    int e0 = sub;
    if (dcap <= 32) {
        int s0 = __shfl(idx, e0, 64);
        int s1 = __shfl(idx, e0 + 4, 64);
        int s2 = __shfl(idx, e0 + 8, 64);
        int s3 = __shfl(idx, e0 + 12, 64);
        int s4 = __shfl(idx, e0 + 16, 64);
        int s5 = __shfl(idx, e0 + 20, 64);
        int s6 = __shfl(idx, e0 + 24, 64);
        int s7 = __shfl(idx, e0 + 28, 64);
        uint4 u0 = *(const uint4*)(xq + (size_t)s0 * 64);
        uint4 u1 = *(const uint4*)(xq + (size_t)s1 * 64);
        uint4 u2 = *(const uint4*)(xq + (size_t)s2 * 64);
        uint4 u3 = *(const uint4*)(xq + (size_t)s3 * 64);
        if (dcap > 16) {
            uint4 u4 = *(const uint4*)(xq + (size_t)s4 * 64);
            uint4 u5 = *(const uint4*)(xq + (size_t)s5 * 64);
            uint4 u6 = *(const uint4*)(xq + (size_t)s6 * 64);
            uint4 u7 = *(const uint4*)(xq + (size_t)s7 * 64);
            acc_u4(u0, acc);
            acc_u4(u1, acc);
            acc_u4(u2, acc);
            acc_u4(u3, acc);
            if (e0 + 16 < dcap) acc_u4(u4, acc);
            if (e0 + 20 < dcap) acc_u4(u5, acc);
            if (e0 + 24 < dcap) acc_u4(u6, acc);
            if (e0 + 28 < dcap) acc_u4(u7, acc);
        } else {
            if (e0 < dcap)      acc_u4(u0, acc);
            if (e0 + 4 < dcap)  acc_u4(u1, acc);
            if (e0 + 8 < dcap)  acc_u4(u2, acc);
            if (e0 + 12 < dcap) acc_u4(u3, acc);
        }
    } else {
        int full = dcap & ~15;
        int b0 = 0;
        for (; b0 < full; b0 += 16) {
            int ee = b0 + sub;
            int s0 = __shfl(idx, ee, 64);
            int s1 = __shfl(idx, ee + 4, 64);
            int s2 = __shfl(idx, ee + 8, 64);
            int s3 = __shfl(idx, ee + 12, 64);
            uint4 u0 = *(const uint4*)(xq + (size_t)s0 * 64);
            uint4 u1 = *(const uint4*)(xq + (size_t)s1 * 64);
            uint4 u2 = *(const uint4*)(xq + (size_t)s2 * 64);
            uint4 u3 = *(const uint4*)(xq + (size_t)s3 * 64);
            acc_u4(u0, acc);
            acc_u4(u1, acc);
            acc_u4(u2, acc);
            acc_u4(u3, acc);
        }
        if (b0 < dcap) {
            int ee = b0 + sub;
            int s0 = __shfl(idx, ee, 64);
            int s1 = __shfl(idx, ee + 4, 64);
            int s2 = __shfl(idx, ee + 8, 64);
            int s3 = __shfl(idx, ee + 12, 64);
            uint4 u0 = *(const uint4*)(xq + (size_t)s0 * 64);
            uint4 u1 = *(const uint4*)(xq + (size_t)s1 * 64);
            uint4 u2 = *(const uint4*)(xq + (size_t)s2 * 64);
            uint4 u3 = *(const uint4*)(xq + (size_t)s3 * 64);
            if (ee < dcap)      acc_u4(u0, acc);
            if (ee + 4 < dcap)  acc_u4(u1, acc);
            if (ee + 8 < dcap)  acc_u4(u2, acc);
            if (ee + 12 < dcap) acc_u4(u3, acc);
        }
        for (int e2 = 64 + sub; e2 < deg; e2 += 4) {
            int s = ss[o0 + e2];
            uint4 u = *(const uint4*)(xq + (size_t)s * 64);
            acc_u4(u, acc);
        }
    }

#pragma unroll
    for (int k = 0; k < 4; k++) {
        acc[k].x += __shfl_down(acc[k].x, 32, 64);
        acc[k].y += __shfl_down(acc[k].y, 32, 64);
        acc[k].x += __shfl_down(acc[k].x, 16, 64);
        acc[k].y += __shfl_down(acc[k].y, 16, 64);
    }
    if (sub == 0) {
        float inv = 1.0f / (float)(deg > 0 ? deg : 1);
        uint4 o;
        o.x = packbf(acc[0].x * inv, acc[0].y * inv);
        o.y = packbf(acc[1].x * inv, acc[1].y * inv);
        o.z = packbf(acc[2].x * inv, acc[2].y * inv);
        o.w = packbf(acc[3].x * inv, acc[3].y * inv);
        *(uint4*)((unsigned*)J.mean[job] + (size_t)node * 64 + q4) = o;
    }
}

// ---------------- bf16 MFMA GEMM, up to 2 jobs per launch, Wf staged in LDS ----------------

struct GemmJobs {
    const unsigned short* A[2][3];
    const unsigned short* Wf[2][3];
    const float* b0[2];
    const float* b1[2];
    unsigned short* outp[2];
    int nmats[2];
};

#define GEMM_BLK ((NA_N + 127) / 128)    // 391 (NA_N == NB_N)

__global__ __launch_bounds__(256) void gemm_mfma_multi_k(GemmJobs J) {
    __shared__ unsigned short Wfs[16384];   // 32 KB: one mat's fragments
    int job = blockIdx.x / GEMM_BLK;
    int blk = blockIdx.x % GEMM_BLK;
    const int nrows = NA_N;
    int lane = threadIdx.x & 63;
    int wv = threadIdx.x >> 6;
    int r0 = blk * 128 + wv * 32;
    int m = lane & 15, quad = lane >> 4;
    int rowA = r0 + m;      if (rowA >= nrows) rowA = nrows - 1;
    int rowB = r0 + 16 + m; if (rowB >= nrows) rowB = nrows - 1;
    int nmats = J.nmats[job];

    float4v acc0[8], acc1[8];
#pragma unroll
    for (int n0 = 0; n0 < 8; n0++) {
        acc0[n0] = (float4v){0.f, 0.f, 0.f, 0.f};
        acc1[n0] = (float4v){0.f, 0.f, 0.f, 0.f};
    }

    for (int mat = 0; mat < nmats; mat++) {
        const unsigned short* A  = J.A[job][mat];
        // stage this mat's fragments into LDS (read once per block, not per wave)
        __syncthreads();
        {
            const uint4* src = (const uint4*)J.Wf[job][mat];
            uint4* dstl = (uint4*)Wfs;
#pragma unroll
            for (int i = 0; i < 8; i++)
                dstl[threadIdx.x * 8 + i] = src[threadIdx.x * 8 + i];
        }
        __syncthreads();
#pragma unroll
        for (int k0i = 0; k0i < 4; k0i++) {
            short8 a0 = *(const short8*)(A + (size_t)rowA * DF + k0i * 32 + quad * 8);
            short8 a1 = *(const short8*)(A + (size_t)rowB * DF + k0i * 32 + quad * 8);
#pragma unroll
            for (int n0 = 0; n0 < 8; n0++) {
                short8 b = *(const short8*)(Wfs + (((n0 * 4 + k0i) * 64 + lane) << 3));
                acc0[n0] = __builtin_amdgcn_mfma_f32_16x16x32_bf16(a0, b, acc0[n0], 0, 0, 0);
                acc1[n0] = __builtin_amdgcn_mfma_f32_16x16x32_bf16(a1, b, acc1[n0], 0, 0, 0);
            }
        }
    }

    const float* b0 = J.b0[job];
    const float* b1 = J.b1[job];
    unsigned short* out = J.outp[job];
#pragma unroll
    for (int n0 = 0; n0 < 8; n0++) {
        int c = n0 * 16 + m;
        float bb = b0[c] + (b1 ? b1[c] : 0.f);
#pragma unroll
        for (int i = 0; i < 4; i++) {
            int r = r0 + quad * 4 + i;
            if (r < nrows) out[(size_t)r * DF + c] = f2bf(fmaxf(acc0[n0][i] + bb, 0.f));
            int r2 = r0 + 16 + quad * 4 + i;
            if (r2 < nrows) out[(size_t)r2 * DF + c] = f2bf(fmaxf(acc1[n0][i] + bb, 0.f));
        }
    }
}

// ---------------- pooling (+ fused head in last block) ----------------

__global__ __launch_bounds__(256) void pool_head_k(
    const unsigned short* __restrict__ xa, const int* __restrict__ batch,
    float* __restrict__ pooled, const int* __restrict__ bound,
    const float* __restrict__ Wout, const float* __restrict__ bout,
    float* __restrict__ out, int* __restrict__ tk) {
    int c2 = threadIdx.x & 63;
    int way = threadIdx.x >> 6;
    int row0 = blockIdx.x * 128;
    int rend = row0 + 128;
    if (rend > NA_N) rend = NA_N;
    const unsigned* x = (const unsigned*)xa;
    float2 acc = {0.f, 0.f};
    int cur_g = -1;
    for (int r = row0 + way; r < rend; r += 4) {
        int g = batch[r];
        if (g != cur_g) {
            if (cur_g >= 0) {
                atomicAdd(&pooled[cur_g * DF + c2 * 2], acc.x);
                atomicAdd(&pooled[cur_g * DF + c2 * 2 + 1], acc.y);
            }
            cur_g = g;
            acc = (float2){0.f, 0.f};
        }
        unsigned d = x[(size_t)r * 64 + c2];
        acc.x += bf_lo(d);
        acc.y += bf_hi(d);
    }
    if (cur_g >= 0) {
        atomicAdd(&pooled[cur_g * DF + c2 * 2], acc.x);
        atomicAdd(&pooled[cur_g * DF + c2 * 2 + 1], acc.y);
    }
    // ---- last-block ticket -> head (bounds precomputed, no binary search) ----
    __threadfence();
    __shared__ int lastf;
    if (threadIdx.x == 0)
        lastf = (atomicAdd(&tk[1], 1) == (int)gridDim.x - 1) ? 1 : 0;
    __syncthreads();
    if (lastf) {
        __threadfence();
        for (int e = threadIdx.x; e < NG_N * NC_N; e += 256) {
            int g = e / NC_N, c = e % NC_N;
            int lo = bound[g], hi = bound[g + 1];
            int cnt = hi - lo;
            float inv = 1.0f / (float)(cnt > 0 ? cnt : 1);
            float s = 0.f;
            for (int k = 0; k < DF; k++) s += pooled[g * DF + k] * Wout[k * NC_N + c];
            out[e] = s * inv + bout[c];
        }
    }
}

// ---------------- launcher ----------------

extern "C" void kernel_launch(void* const* d_in, const int* in_sizes, int n_in,
                              void* d_out, int out_size, void* d_ws, size_t ws_size,
                              hipStream_t stream) {
    const float* x_a = (const float*)d_in[0];
    const float* x_b = (const float*)d_in[1];
    const int* ei_aa = (const int*)d_in[2];
    const int* ei_ab = (const int*)d_in[3];
    const int* ei_ba = (const int*)d_in[4];
    const int* batch = (const int*)d_in[5];
    const float *Wn0_aa = (const float*)d_in[6],  *bn0_aa = (const float*)d_in[7],  *Wr0_aa = (const float*)d_in[8];
    const float *Wn0_ab = (const float*)d_in[9],  *bn0_ab = (const float*)d_in[10], *Wr0_ab = (const float*)d_in[11];
    const float *Wn0_ba = (const float*)d_in[12], *bn0_ba = (const float*)d_in[13], *Wr0_ba = (const float*)d_in[14];
    const float *Wn1_aa = (const float*)d_in[15], *bn1_aa = (const float*)d_in[16], *Wr1_aa = (const float*)d_in[17];
    // d_in[18..20] unused (layer-2 out_b never consumed)
    const float *Wn1_ba = (const float*)d_in[21], *bn1_ba = (const float*)d_in[22], *Wr1_ba = (const float*)d_in[23];
    const float *W_out = (const float*)d_in[24], *b_out = (const float*)d_in[25];
    float* out = (float*)d_out;

    char* w = (char*)d_ws;
    size_t off = 0;
    auto alloc = [&](size_t b) -> char* {
        char* p = w + off;
        off += (b + 255) & ~(size_t)255;
        return p;
    };

    int* offs_aa = (int*)alloc((NA_N + 1) * 4);
    int* ss_aa   = (int*)alloc((size_t)NE * 4);
    int* offs_ba = (int*)alloc((NA_N + 1) * 4);
    int* ss_ba   = (int*)alloc((size_t)NE * 4);
    int* offs_ab = (int*)alloc((NB_N + 1) * 4);
    int* ss_ab   = (int*)alloc((size_t)NE * 4);
    // contiguous zero region: bcnt3 (3*NBUK ints, padded to 4864) + tickets
    int* bcnt3 = (int*)alloc(3 * NBUK * 4);     // padded to 4864 B by alloc
    int* tk    = (int*)alloc(8);                // tk[0]=prep ticket, tk[1]=pool ticket
    int* bbase3 = (int*)alloc(3 * (NBUK + 1) * 4);
    int* bcur3  = (int*)alloc(3 * NBUK * 4);
    unsigned* ebuf0 = (unsigned*)alloc((size_t)NE * 4);
    unsigned* ebuf1 = (unsigned*)alloc((size_t)NE * 4);
    unsigned* ebuf2 = (unsigned*)alloc((size_t)NE * 4);

    unsigned short* xa_bf   = (unsigned short*)alloc((size_t)NA_N * DF * 2);
    unsigned short* xb_bf   = (unsigned short*)alloc((size_t)NB_N * DF * 2);
    unsigned short* mean_aa = (unsigned short*)alloc((size_t)NA_N * DF * 2);
    unsigned short* mean_ba = (unsigned short*)alloc((size_t)NA_N * DF * 2);
    unsigned short* mean_ab = (unsigned short*)alloc((size_t)NB_N * DF * 2);
    unsigned short* xa1 = (unsigned short*)alloc((size_t)NA_N * DF * 2);
    unsigned short* xb1 = (unsigned short*)alloc((size_t)NB_N * DF * 2);
    unsigned short* xa2 = mean_ab;  // alias: mean_ab dead once layer-0 dst-b GEMM ran
    unsigned short* Wf[8];
    for (int i = 0; i < 8; i++) Wf[i] = (unsigned short*)alloc((size_t)DF * DF * 2);
    float* pooled = (float*)alloc(NG_N * DF * 4);
    int* bound = (int*)alloc((NG_N + 1) * 4);

    // ---- CSR jobs ----
    CsrJobs CJ;
    CJ.src[0] = ei_aa;      CJ.dst[0] = ei_aa + NE;
    CJ.src[1] = ei_ba;      CJ.dst[1] = ei_ba + NE;
    CJ.src[2] = ei_ab;      CJ.dst[2] = ei_ab + NE;
    CJ.offs[0] = offs_aa;   CJ.ss[0] = ss_aa;   CJ.ebuf[0] = ebuf0;
    CJ.offs[1] = offs_ba;   CJ.ss[1] = ss_ba;   CJ.ebuf[1] = ebuf1;
    CJ.offs[2] = offs_ab;   CJ.ss[2] = ss_ab;   CJ.ebuf[2] = ebuf2;

    WJobs WJ;
    WJ.a[0] = Wn0_aa; WJ.b[0] = nullptr; WJ.d[0] = Wf[0];
    WJ.a[1] = Wn0_ba; WJ.b[1] = nullptr; WJ.d[1] = Wf[1];
    WJ.a[2] = Wr0_aa; WJ.b[2] = Wr0_ba;  WJ.d[2] = Wf[2];
    WJ.a[3] = Wn0_ab; WJ.b[3] = nullptr; WJ.d[3] = Wf[3];
    WJ.a[4] = Wr0_ab; WJ.b[4] = nullptr; WJ.d[4] = Wf[4];
    WJ.a[5] = Wn1_aa; WJ.b[5] = nullptr; WJ.d[5] = Wf[5];
    WJ.a[6] = Wn1_ba; WJ.b[6] = nullptr; WJ.d[6] = Wf[6];
    WJ.a[7] = Wr1_aa; WJ.b[7] = Wr1_ba;  WJ.d[7] = Wf[7];

    // ---- zero bcnt3 + tickets (contiguous; bcnt3 padded region is 4864 B) ----
    hipMemsetAsync(bcnt3, 0, 4864 + 8, stream);
    // ---- prep + hist + (last-block) scan ----
    prep_hist_k<<<PREP_BLKS + 3 * BINBLK, 256, 0, stream>>>(
        x_a, x_b, xa_bf, xb_bf, WJ, pooled, batch, bound, CJ, bcnt3, bbase3, bcur3, tk);
    bucket_bin3_k<<<3 * BINBLK, 256, 0, stream>>>(CJ, bcur3);
    bucket_sort3_k<<<3 * NBUK, 256, 0, stream>>>(CJ, bbase3, NA_N);

    // ---- layer 0: 3 aggregations fused ----
    AggJobs A0;
    A0.xs[0] = xa_bf; A0.offs[0] = offs_aa; A0.ss[0] = ss_aa; A0.mean[0] = mean_aa;
    A0.xs[1] = xb_bf; A0.offs[1] = offs_ba; A0.ss[1] = ss_ba; A0.mean[1] = mean_ba;
    A0.xs[2] = xa_bf; A0.offs[2] = offs_ab; A0.ss[2] = ss_ab; A0.mean[2] = mean_ab;
    aggregate_multi_k<<<3 * AGGBLK, 256, 0, stream>>>(A0);

    // ---- layer 0: both GEMMs in one launch ----
    GemmJobs G0;
    G0.A[0][0] = mean_aa; G0.Wf[0][0] = Wf[0];
    G0.A[0][1] = mean_ba; G0.Wf[0][1] = Wf[1];
    G0.A[0][2] = xa_bf;   G0.Wf[0][2] = Wf[2];
    G0.b0[0] = bn0_aa; G0.b1[0] = bn0_ba; G0.outp[0] = xa1; G0.nmats[0] = 3;
    G0.A[1][0] = mean_ab; G0.Wf[1][0] = Wf[3];
    G0.A[1][1] = xb_bf;   G0.Wf[1][1] = Wf[4];
    G0.A[1][2] = nullptr; G0.Wf[1][2] = nullptr;
    G0.b0[1] = bn0_ab; G0.b1[1] = nullptr; G0.outp[1] = xb1; G0.nmats[1] = 2;
    gemm_mfma_multi_k<<<2 * GEMM_BLK, 256, 0, stream>>>(G0);

    // ---- layer 1: 2 aggregations fused (out_b unused downstream -> skipped) ----
    AggJobs A1;
    A1.xs[0] = xa1; A1.offs[0] = offs_aa; A1.ss[0] = ss_aa; A1.mean[0] = mean_aa;
    A1.xs[1] = xb1; A1.offs[1] = offs_ba; A1.ss[1] = ss_ba; A1.mean[1] = mean_ba;
    A1.xs[2] = xa1; A1.offs[2] = offs_aa; A1.ss[2] = ss_aa; A1.mean[2] = mean_aa; // unused
    aggregate_multi_k<<<2 * AGGBLK, 256, 0, stream>>>(A1);

    // ---- layer 1 GEMM ----
    GemmJobs G1;
    G1.A[0][0] = mean_aa; G1.Wf[0][0] = Wf[5];
    G1.A[0][1] = mean_ba; G1.Wf[0][1] = Wf[6];
    G1.A[0][2] = xa1;     G1.Wf[0][2] = Wf[7];
    G1.b0[0] = bn1_aa; G1.b1[0] = bn1_ba; G1.outp[0] = xa2; G1.nmats[0] = 3;
    G1.A[1][0] = nullptr; G1.Wf[1][0] = nullptr;
    G1.A[1][1] = nullptr; G1.Wf[1][1] = nullptr;
    G1.A[1][2] = nullptr; G1.Wf[1][2] = nullptr;
    G1.b0[1] = nullptr; G1.b1[1] = nullptr; G1.outp[1] = nullptr; G1.nmats[1] = 0;
    gemm_mfma_multi_k<<<GEMM_BLK, 256, 0, stream>>>(G1);

    // ---- pool + (last-block) head ----
    pool_head_k<<<(NA_N + 127) / 128, 256, 0, stream>>>(
        xa2, batch, pooled, bound, W_out, b_out, out, tk);
}

// Round 12
// 442.198 us; speedup vs baseline: 3.6883x; 3.6883x over previous
//
#include <hip/hip_runtime.h>

#define NA_N 50000
#define NB_N 50000
#define NE   1000000
#define DF   128
#define NG_N 64
#define NC_N 10

// bucketed counting sort params
#define BSHIFT 7
#define BNODES 128
#define NBUK   391
#define CHB    4096
#define NIT    (CHB / 256)
#define BINBLK ((NE + CHB - 1) / CHB)    // 245
#define AGGBLK ((NA_N * 64) / 256)       // 12500 blocks per aggregation job

#define CN4A (NA_N * DF / 4)
#define CN4T ((NA_N + NB_N) * DF / 4)
#define WELEMS (8 * 16384)
#define PZ4 (NG_N * DF / 4)
#define PREP_ITEMS (CN4T + WELEMS + PZ4 + NA_N)
#define PREP_BLKS ((PREP_ITEMS + 255) / 256)

typedef __attribute__((ext_vector_type(8))) short short8;
typedef __attribute__((ext_vector_type(4))) float float4v;
typedef __attribute__((ext_vector_type(2))) float v2f;

__device__ __forceinline__ unsigned short f2bf(float f) {
    unsigned u = __float_as_uint(f);
    unsigned r = (u + 0x7fff + ((u >> 16) & 1)) >> 16;   // RNE
    return (unsigned short)r;
}
__device__ __forceinline__ float bf_lo(unsigned d) { return __uint_as_float(d << 16); }
__device__ __forceinline__ float bf_hi(unsigned d) { return __uint_as_float(d & 0xffff0000u); }
__device__ __forceinline__ v2f bfpair(unsigned d) { return (v2f){bf_lo(d), bf_hi(d)}; }
__device__ __forceinline__ unsigned packbf(float lo, float hi) {
    return (unsigned)f2bf(lo) | ((unsigned)f2bf(hi) << 16);
}

struct WJobs {
    const float* a[8];
    const float* b[8];
    unsigned short* d[8];
};

struct CsrJobs {
    const int* src[3];
    const int* dst[3];
    int* offs[3];
    int* ss[3];
    unsigned* ebuf[3];
};

// ---------------- prep (convert + weights + pooled zero + graph bounds) + hist ----------------
// NOTE (R11 lesson): NO last-block-ticket / __threadfence here. Device-scope
// fences on gfx950 force cross-XCD L2 writebacks (~serialized flush per block)
// and cost 100x more than the launch boundary they replace.

__global__ __launch_bounds__(256) void prep_hist_k(
        const float* __restrict__ xa, const float* __restrict__ xb,
        unsigned short* __restrict__ ya, unsigned short* __restrict__ yb,
        WJobs WJ, float* __restrict__ pooled,
        const int* __restrict__ batch, int* __restrict__ bound,
        CsrJobs CJ, int* __restrict__ bcnt3) {
    if ((int)blockIdx.x < PREP_BLKS) {
        int i = blockIdx.x * 256 + threadIdx.x;
        if (i < CN4T) {
            const float* x = (i < CN4A) ? xa : xb;
            unsigned short* y = (i < CN4A) ? ya : yb;
            int j = (i < CN4A) ? i : i - CN4A;
            float4 v = ((const float4*)x)[j];
            uint2 o;
            o.x = packbf(v.x, v.y);
            o.y = packbf(v.z, v.w);
            ((uint2*)y)[j] = o;
        } else if (i < CN4T + WELEMS) {
            int t = i - CN4T;
            int which = t >> 14;
            t &= 16383;
            int j = t & 7, lane = (t >> 3) & 63, k0i = (t >> 9) & 3, n0 = t >> 11;
            int k = k0i * 32 + (lane >> 4) * 8 + j;
            int n = n0 * 16 + (lane & 15);
            float v = WJ.a[which][k * DF + n];
            if (WJ.b[which]) v += WJ.b[which][k * DF + n];
            WJ.d[which][t] = f2bf(v);
        } else if (i < CN4T + WELEMS + PZ4) {
            int t = i - CN4T - WELEMS;
            ((float4*)pooled)[t] = (float4){0.f, 0.f, 0.f, 0.f};
        } else if (i < PREP_ITEMS) {
            // graph boundary precompute over sorted batch
            int rr = i - (CN4T + WELEMS + PZ4);
            int c = batch[rr];
            if (rr == 0) {
                for (int g = 0; g <= c; g++) bound[g] = 0;
            } else {
                int p = batch[rr - 1];
                for (int g = p + 1; g <= c; g++) bound[g] = rr;
            }
            if (rr == NA_N - 1) {
                for (int g = c + 1; g <= NG_N; g++) bound[g] = NA_N;
            }
        }
        return;
    }
    // bucket histogram part
    int hb = blockIdx.x - PREP_BLKS;
    int which = hb / BINBLK;
    int blk = hb % BINBLK;
    const int* dst = CJ.dst[which];
    int* bcnt = bcnt3 + which * NBUK;
    __shared__ int h[NBUK];
    for (int i = threadIdx.x; i < NBUK; i += 256) h[i] = 0;
    __syncthreads();
    int base = blk * CHB;
#pragma unroll
    for (int it = 0; it < NIT; it++) {
        int i = base + it * 256 + threadIdx.x;
        if (i < NE) atomicAdd(&h[dst[i] >> BSHIFT], 1);
    }
    __syncthreads();
    for (int i = threadIdx.x; i < NBUK; i += 256)
        if (h[i]) atomicAdd(&bcnt[i], h[i]);
}

// ---------------- CSR build (scan / bin / sort) ----------------

__global__ void bucket_scan3_k(const int* __restrict__ bcnt3,
                               int* __restrict__ bbase3, int* __restrict__ bcur3) {
    __shared__ int s[512];
    int which = blockIdx.x;
    const int* bcnt = bcnt3 + which * NBUK;
    int* bbase = bbase3 + which * (NBUK + 1);
    int* bcur = bcur3 + which * NBUK;
    int t = threadIdx.x;
    int v = (t < NBUK) ? bcnt[t] : 0;
    s[t] = v;
    __syncthreads();
    for (int d = 1; d < 512; d <<= 1) {
        int x = (t >= d) ? s[t - d] : 0;
        __syncthreads();
        if (t >= d) s[t] += x;
        __syncthreads();
    }
    if (t < NBUK) {
        int e = s[t] - v;
        bbase[t] = e;
        bcur[t] = e;
    }
    if (t == 0) bbase[NBUK] = NE;
}

__global__ __launch_bounds__(256) void bucket_bin3_k(CsrJobs J, int* __restrict__ bcur3) {
    int which = blockIdx.x / BINBLK;
    int blk = blockIdx.x % BINBLK;
    const int* src = J.src[which];
    const int* dst = J.dst[which];
    int* bcur = bcur3 + which * NBUK;
    unsigned* ebuf = J.ebuf[which];
    __shared__ int cnt[NBUK];
    __shared__ int chunk[NBUK];
    for (int i = threadIdx.x; i < NBUK; i += 256) cnt[i] = 0;
    __syncthreads();
    int base = blk * CHB;
    int bk[NIT], rk[NIT];
    unsigned sv[NIT];
#pragma unroll
    for (int it = 0; it < NIT; it++) {
        int i = base + it * 256 + threadIdx.x;
        if (i < NE) {
            int d = dst[i];
            int b = d >> BSHIFT;
            bk[it] = b;
            rk[it] = atomicAdd(&cnt[b], 1);
            sv[it] = (unsigned)src[i] | ((unsigned)(d & (BNODES - 1)) << 24);
        } else {
            bk[it] = -1;
        }
    }
    __syncthreads();
    for (int i = threadIdx.x; i < NBUK; i += 256)
        chunk[i] = cnt[i] ? atomicAdd(&bcur[i], cnt[i]) : 0;
    __syncthreads();
#pragma unroll
    for (int it = 0; it < NIT; it++)
        if (bk[it] >= 0) ebuf[chunk[bk[it]] + rk[it]] = sv[it];
}

__global__ __launch_bounds__(256) void bucket_sort3_k(CsrJobs J, const int* __restrict__ bbase3,
                                                      int ndst) {
    __shared__ int hist[BNODES];
    __shared__ int loffs[BNODES];
    int which = blockIdx.x / NBUK;
    int b = blockIdx.x % NBUK;
    const unsigned* ebuf = J.ebuf[which];
    const int* bbase = bbase3 + which * (NBUK + 1);
    int* offs = J.offs[which];
    int* ss = J.ss[which];
    int t = threadIdx.x;
    int ebase = bbase[b], ecnt = bbase[b + 1] - ebase;
    if (t < BNODES) hist[t] = 0;
    __syncthreads();
    for (int e = t; e < ecnt; e += 256)
        atomicAdd(&hist[ebuf[ebase + e] >> 24], 1);
    __syncthreads();
    if (t < BNODES) loffs[t] = hist[t];
    __syncthreads();
    for (int d = 1; d < BNODES; d <<= 1) {
        int x = 0;
        if (t < BNODES && t >= d) x = loffs[t - d];
        __syncthreads();
        if (t < BNODES && t >= d) loffs[t] += x;
        __syncthreads();
    }
    if (t < BNODES) {
        int ex = loffs[t] - hist[t];
        loffs[t] = ex;
        int gnode = b * BNODES + t;
        if (gnode < ndst) offs[gnode] = ebase + ex;
        hist[t] = 0;
    }
    if (b == 0 && t == 0) offs[ndst] = NE;
    __syncthreads();
    for (int e = t; e < ecnt; e += 256) {
        unsigned w = ebuf[ebase + e];
        int dl = w >> 24;
        int r = atomicAdd(&hist[dl], 1);
        ss[ebase + loffs[dl] + r] = (int)(w & 0xFFFFFF);
    }
}

// ---------------- segment mean (at its structural floor: ~281 MB L2-fill / dispatch) ----------------

struct AggJobs {
    const unsigned short* xs[3];
    const int* offs[3];
    const int* ss[3];
    unsigned short* mean[3];
};

__device__ __forceinline__ void acc_u4(uint4 u, v2f acc[4]) {
    acc[0] += bfpair(u.x);
    acc[1] += bfpair(u.y);
    acc[2] += bfpair(u.z);
    acc[3] += bfpair(u.w);
}

__global__ __launch_bounds__(256) void aggregate_multi_k(AggJobs J) {
    int job = blockIdx.x / AGGBLK;
    int blk = blockIdx.x % AGGBLK;
    int node = (blk * 256 + threadIdx.x) >> 6;
    int lane = threadIdx.x & 63;
    const unsigned* xs = (const unsigned*)J.xs[job];
    const int* offs = J.offs[job];
    const int* ss = J.ss[job];
    int o0 = offs[node], o1 = offs[node + 1];
    int deg = o1 - o0;
    int idx = (lane < deg) ? ss[o0 + lane] : 0;
    int sub = lane >> 4;
    int q4 = (lane & 15) * 4;
    const unsigned* xq = xs + q4;
    v2f acc[4];
#pragma unroll
    for (int k = 0; k < 4; k++) acc[k] = (v2f){0.f, 0.f};

    int dcap = deg < 64 ? deg : 64;
    int e0 = sub;
    if (dcap <= 32) {
        int s0 = __shfl(idx, e0, 64);
        int s1 = __shfl(idx, e0 + 4, 64);
        int s2 = __shfl(idx, e0 + 8, 64);
        int s3 = __shfl(idx, e0 + 12, 64);
        int s4 = __shfl(idx, e0 + 16, 64);
        int s5 = __shfl(idx, e0 + 20, 64);
        int s6 = __shfl(idx, e0 + 24, 64);
        int s7 = __shfl(idx, e0 + 28, 64);
        uint4 u0 = *(const uint4*)(xq + (size_t)s0 * 64);
        uint4 u1 = *(const uint4*)(xq + (size_t)s1 * 64);
        uint4 u2 = *(const uint4*)(xq + (size_t)s2 * 64);
        uint4 u3 = *(const uint4*)(xq + (size_t)s3 * 64);
        if (dcap > 16) {
            uint4 u4 = *(const uint4*)(xq + (size_t)s4 * 64);
            uint4 u5 = *(const uint4*)(xq + (size_t)s5 * 64);
            uint4 u6 = *(const uint4*)(xq + (size_t)s6 * 64);
            uint4 u7 = *(const uint4*)(xq + (size_t)s7 * 64);
            acc_u4(u0, acc);
            acc_u4(u1, acc);
            acc_u4(u2, acc);
            acc_u4(u3, acc);
            if (e0 + 16 < dcap) acc_u4(u4, acc);
            if (e0 + 20 < dcap) acc_u4(u5, acc);
            if (e0 + 24 < dcap) acc_u4(u6, acc);
            if (e0 + 28 < dcap) acc_u4(u7, acc);
        } else {
            if (e0 < dcap)      acc_u4(u0, acc);
            if (e0 + 4 < dcap)  acc_u4(u1, acc);
            if (e0 + 8 < dcap)  acc_u4(u2, acc);
            if (e0 + 12 < dcap) acc_u4(u3, acc);
        }
    } else {
        int full = dcap & ~15;
        int b0 = 0;
        for (; b0 < full; b0 += 16) {
            int ee = b0 + sub;
            int s0 = __shfl(idx, ee, 64);
            int s1 = __shfl(idx, ee + 4, 64);
            int s2 = __shfl(idx, ee + 8, 64);
            int s3 = __shfl(idx, ee + 12, 64);
            uint4 u0 = *(const uint4*)(xq + (size_t)s0 * 64);
            uint4 u1 = *(const uint4*)(xq + (size_t)s1 * 64);
            uint4 u2 = *(const uint4*)(xq + (size_t)s2 * 64);
            uint4 u3 = *(const uint4*)(xq + (size_t)s3 * 64);
            acc_u4(u0, acc);
            acc_u4(u1, acc);
            acc_u4(u2, acc);
            acc_u4(u3, acc);
        }
        if (b0 < dcap) {
            int ee = b0 + sub;
            int s0 = __shfl(idx, ee, 64);
            int s1 = __shfl(idx, ee + 4, 64);
            int s2 = __shfl(idx, ee + 8, 64);
            int s3 = __shfl(idx, ee + 12, 64);
            uint4 u0 = *(const uint4*)(xq + (size_t)s0 * 64);
            uint4 u1 = *(const uint4*)(xq + (size_t)s1 * 64);
            uint4 u2 = *(const uint4*)(xq + (size_t)s2 * 64);
            uint4 u3 = *(const uint4*)(xq + (size_t)s3 * 64);
            if (ee < dcap)      acc_u4(u0, acc);
            if (ee + 4 < dcap)  acc_u4(u1, acc);
            if (ee + 8 < dcap)  acc_u4(u2, acc);
            if (ee + 12 < dcap) acc_u4(u3, acc);
        }
        for (int e2 = 64 + sub; e2 < deg; e2 += 4) {
            int s = ss[o0 + e2];
            uint4 u = *(const uint4*)(xq + (size_t)s * 64);
            acc_u4(u, acc);
        }
    }

#pragma unroll
    for (int k = 0; k < 4; k++) {
        acc[k].x += __shfl_down(acc[k].x, 32, 64);
        acc[k].y += __shfl_down(acc[k].y, 32, 64);
        acc[k].x += __shfl_down(acc[k].x, 16, 64);
        acc[k].y += __shfl_down(acc[k].y, 16, 64);
    }
    if (sub == 0) {
        float inv = 1.0f / (float)(deg > 0 ? deg : 1);
        uint4 o;
        o.x = packbf(acc[0].x * inv, acc[0].y * inv);
        o.y = packbf(acc[1].x * inv, acc[1].y * inv);
        o.z = packbf(acc[2].x * inv, acc[2].y * inv);
        o.w = packbf(acc[3].x * inv, acc[3].y * inv);
        *(uint4*)((unsigned*)J.mean[job] + (size_t)node * 64 + q4) = o;
    }
}

// ---------------- bf16 MFMA GEMM, up to 2 jobs per launch, Wf staged in LDS ----------------

struct GemmJobs {
    const unsigned short* A[2][3];
    const unsigned short* Wf[2][3];
    const float* b0[2];
    const float* b1[2];
    unsigned short* outp[2];
    int nmats[2];
};

#define GEMM_BLK ((NA_N + 127) / 128)    // 391 (NA_N == NB_N)

__global__ __launch_bounds__(256) void gemm_mfma_multi_k(GemmJobs J) {
    __shared__ unsigned short Wfs[16384];   // 32 KB: one mat's fragments
    int job = blockIdx.x / GEMM_BLK;
    int blk = blockIdx.x % GEMM_BLK;
    const int nrows = NA_N;
    int lane = threadIdx.x & 63;
    int wv = threadIdx.x >> 6;
    int r0 = blk * 128 + wv * 32;
    int m = lane & 15, quad = lane >> 4;
    int rowA = r0 + m;      if (rowA >= nrows) rowA = nrows - 1;
    int rowB = r0 + 16 + m; if (rowB >= nrows) rowB = nrows - 1;
    int nmats = J.nmats[job];

    float4v acc0[8], acc1[8];
#pragma unroll
    for (int n0 = 0; n0 < 8; n0++) {
        acc0[n0] = (float4v){0.f, 0.f, 0.f, 0.f};
        acc1[n0] = (float4v){0.f, 0.f, 0.f, 0.f};
    }

    for (int mat = 0; mat < nmats; mat++) {
        const unsigned short* A  = J.A[job][mat];
        // stage this mat's fragments into LDS (read once per block, not per wave)
        __syncthreads();
        {
            const uint4* src = (const uint4*)J.Wf[job][mat];
            uint4* dstl = (uint4*)Wfs;
#pragma unroll
            for (int i = 0; i < 8; i++)
                dstl[threadIdx.x * 8 + i] = src[threadIdx.x * 8 + i];
        }
        __syncthreads();
#pragma unroll
        for (int k0i = 0; k0i < 4; k0i++) {
            short8 a0 = *(const short8*)(A + (size_t)rowA * DF + k0i * 32 + quad * 8);
            short8 a1 = *(const short8*)(A + (size_t)rowB * DF + k0i * 32 + quad * 8);
#pragma unroll
            for (int n0 = 0; n0 < 8; n0++) {
                short8 b = *(const short8*)(Wfs + (((n0 * 4 + k0i) * 64 + lane) << 3));
                acc0[n0] = __builtin_amdgcn_mfma_f32_16x16x32_bf16(a0, b, acc0[n0], 0, 0, 0);
                acc1[n0] = __builtin_amdgcn_mfma_f32_16x16x32_bf16(a1, b, acc1[n0], 0, 0, 0);
            }
        }
    }

    const float* b0 = J.b0[job];
    const float* b1 = J.b1[job];
    unsigned short* out = J.outp[job];
#pragma unroll
    for (int n0 = 0; n0 < 8; n0++) {
        int c = n0 * 16 + m;
        float bb = b0[c] + (b1 ? b1[c] : 0.f);
#pragma unroll
        for (int i = 0; i < 4; i++) {
            int r = r0 + quad * 4 + i;
            if (r < nrows) out[(size_t)r * DF + c] = f2bf(fmaxf(acc0[n0][i] + bb, 0.f));
            int r2 = r0 + 16 + quad * 4 + i;
            if (r2 < nrows) out[(size_t)r2 * DF + c] = f2bf(fmaxf(acc1[n0][i] + bb, 0.f));
        }
    }
}

// ---------------- pooling + head (separate launches; launch boundary = cheap fence) ----------------

__global__ __launch_bounds__(256) void pool_partial_k(
    const unsigned short* __restrict__ xa, const int* __restrict__ batch,
    float* __restrict__ pooled) {
    int c2 = threadIdx.x & 63;
    int way = threadIdx.x >> 6;
    int row0 = blockIdx.x * 128;
    int rend = row0 + 128;
    if (rend > NA_N) rend = NA_N;
    const unsigned* x = (const unsigned*)xa;
    float2 acc = {0.f, 0.f};
    int cur_g = -1;
    for (int r = row0 + way; r < rend; r += 4) {
        int g = batch[r];
        if (g != cur_g) {
            if (cur_g >= 0) {
                atomicAdd(&pooled[cur_g * DF + c2 * 2], acc.x);
                atomicAdd(&pooled[cur_g * DF + c2 * 2 + 1], acc.y);
            }
            cur_g = g;
            acc = (float2){0.f, 0.f};
        }
        unsigned d = x[(size_t)r * 64 + c2];
        acc.x += bf_lo(d);
        acc.y += bf_hi(d);
    }
    if (cur_g >= 0) {
        atomicAdd(&pooled[cur_g * DF + c2 * 2], acc.x);
        atomicAdd(&pooled[cur_g * DF + c2 * 2 + 1], acc.y);
    }
}

__global__ void out_head_k(const float* __restrict__ pooled, const int* __restrict__ bound,
                           const float* __restrict__ Wout, const float* __restrict__ bout,
                           float* __restrict__ out) {
    int tid = threadIdx.x;
    if (tid >= NG_N * NC_N) return;
    int g = tid / NC_N, c = tid % NC_N;
    int lo = bound[g], hi = bound[g + 1];
    int cnt = hi - lo;
    float inv = 1.0f / (float)(cnt > 0 ? cnt : 1);
    float s = 0.f;
    for (int k = 0; k < DF; k++) s += pooled[g * DF + k] * Wout[k * NC_N + c];
    out[tid] = s * inv + bout[c];
}

// ---------------- launcher ----------------

extern "C" void kernel_launch(void* const* d_in, const int* in_sizes, int n_in,
                              void* d_out, int out_size, void* d_ws, size_t ws_size,
                              hipStream_t stream) {
    const float* x_a = (const float*)d_in[0];
    const float* x_b = (const float*)d_in[1];
    const int* ei_aa = (const int*)d_in[2];
    const int* ei_ab = (const int*)d_in[3];
    const int* ei_ba = (const int*)d_in[4];
    const int* batch = (const int*)d_in[5];
    const float *Wn0_aa = (const float*)d_in[6],  *bn0_aa = (const float*)d_in[7],  *Wr0_aa = (const float*)d_in[8];
    const float *Wn0_ab = (const float*)d_in[9],  *bn0_ab = (const float*)d_in[10], *Wr0_ab = (const float*)d_in[11];
    const float *Wn0_ba = (const float*)d_in[12], *bn0_ba = (const float*)d_in[13], *Wr0_ba = (const float*)d_in[14];
    const float *Wn1_aa = (const float*)d_in[15], *bn1_aa = (const float*)d_in[16], *Wr1_aa = (const float*)d_in[17];
    // d_in[18..20] unused (layer-2 out_b never consumed)
    const float *Wn1_ba = (const float*)d_in[21], *bn1_ba = (const float*)d_in[22], *Wr1_ba = (const float*)d_in[23];
    const float *W_out = (const float*)d_in[24], *b_out = (const float*)d_in[25];
    float* out = (float*)d_out;

    char* w = (char*)d_ws;
    size_t off = 0;
    auto alloc = [&](size_t b) -> char* {
        char* p = w + off;
        off += (b + 255) & ~(size_t)255;
        return p;
    };

    int* offs_aa = (int*)alloc((NA_N + 1) * 4);
    int* ss_aa   = (int*)alloc((size_t)NE * 4);
    int* offs_ba = (int*)alloc((NA_N + 1) * 4);
    int* ss_ba   = (int*)alloc((size_t)NE * 4);
    int* offs_ab = (int*)alloc((NB_N + 1) * 4);
    int* ss_ab   = (int*)alloc((size_t)NE * 4);
    int* bcnt3  = (int*)alloc(3 * NBUK * 4);
    int* bbase3 = (int*)alloc(3 * (NBUK + 1) * 4);
    int* bcur3  = (int*)alloc(3 * NBUK * 4);
    unsigned* ebuf0 = (unsigned*)alloc((size_t)NE * 4);
    unsigned* ebuf1 = (unsigned*)alloc((size_t)NE * 4);
    unsigned* ebuf2 = (unsigned*)alloc((size_t)NE * 4);

    unsigned short* xa_bf   = (unsigned short*)alloc((size_t)NA_N * DF * 2);
    unsigned short* xb_bf   = (unsigned short*)alloc((size_t)NB_N * DF * 2);
    unsigned short* mean_aa = (unsigned short*)alloc((size_t)NA_N * DF * 2);
    unsigned short* mean_ba = (unsigned short*)alloc((size_t)NA_N * DF * 2);
    unsigned short* mean_ab = (unsigned short*)alloc((size_t)NB_N * DF * 2);
    unsigned short* xa1 = (unsigned short*)alloc((size_t)NA_N * DF * 2);
    unsigned short* xb1 = (unsigned short*)alloc((size_t)NB_N * DF * 2);
    unsigned short* xa2 = mean_ab;  // alias: mean_ab dead once layer-0 dst-b GEMM ran
    unsigned short* Wf[8];
    for (int i = 0; i < 8; i++) Wf[i] = (unsigned short*)alloc((size_t)DF * DF * 2);
    float* pooled = (float*)alloc(NG_N * DF * 4);
    int* bound = (int*)alloc((NG_N + 1) * 4);

    // ---- CSR jobs ----
    CsrJobs CJ;
    CJ.src[0] = ei_aa;      CJ.dst[0] = ei_aa + NE;
    CJ.src[1] = ei_ba;      CJ.dst[1] = ei_ba + NE;
    CJ.src[2] = ei_ab;      CJ.dst[2] = ei_ab + NE;
    CJ.offs[0] = offs_aa;   CJ.ss[0] = ss_aa;   CJ.ebuf[0] = ebuf0;
    CJ.offs[1] = offs_ba;   CJ.ss[1] = ss_ba;   CJ.ebuf[1] = ebuf1;
    CJ.offs[2] = offs_ab;   CJ.ss[2] = ss_ab;   CJ.ebuf[2] = ebuf2;

    WJobs WJ;
    WJ.a[0] = Wn0_aa; WJ.b[0] = nullptr; WJ.d[0] = Wf[0];
    WJ.a[1] = Wn0_ba; WJ.b[1] = nullptr; WJ.d[1] = Wf[1];
    WJ.a[2] = Wr0_aa; WJ.b[2] = Wr0_ba;  WJ.d[2] = Wf[2];
    WJ.a[3] = Wn0_ab; WJ.b[3] = nullptr; WJ.d[3] = Wf[3];
    WJ.a[4] = Wr0_ab; WJ.b[4] = nullptr; WJ.d[4] = Wf[4];
    WJ.a[5] = Wn1_aa; WJ.b[5] = nullptr; WJ.d[5] = Wf[5];
    WJ.a[6] = Wn1_ba; WJ.b[6] = nullptr; WJ.d[6] = Wf[6];
    WJ.a[7] = Wr1_aa; WJ.b[7] = Wr1_ba;  WJ.d[7] = Wf[7];

    // ---- prep + hist, then scan/bin/sort ----
    hipMemsetAsync(bcnt3, 0, 3 * NBUK * sizeof(int), stream);
    prep_hist_k<<<PREP_BLKS + 3 * BINBLK, 256, 0, stream>>>(
        x_a, x_b, xa_bf, xb_bf, WJ, pooled, batch, bound, CJ, bcnt3);
    bucket_scan3_k<<<3, 512, 0, stream>>>(bcnt3, bbase3, bcur3);
    bucket_bin3_k<<<3 * BINBLK, 256, 0, stream>>>(CJ, bcur3);
    bucket_sort3_k<<<3 * NBUK, 256, 0, stream>>>(CJ, bbase3, NA_N);

    // ---- layer 0: 3 aggregations fused ----
    AggJobs A0;
    A0.xs[0] = xa_bf; A0.offs[0] = offs_aa; A0.ss[0] = ss_aa; A0.mean[0] = mean_aa;
    A0.xs[1] = xb_bf; A0.offs[1] = offs_ba; A0.ss[1] = ss_ba; A0.mean[1] = mean_ba;
    A0.xs[2] = xa_bf; A0.offs[2] = offs_ab; A0.ss[2] = ss_ab; A0.mean[2] = mean_ab;
    aggregate_multi_k<<<3 * AGGBLK, 256, 0, stream>>>(A0);

    // ---- layer 0: both GEMMs in one launch ----
    GemmJobs G0;
    G0.A[0][0] = mean_aa; G0.Wf[0][0] = Wf[0];
    G0.A[0][1] = mean_ba; G0.Wf[0][1] = Wf[1];
    G0.A[0][2] = xa_bf;   G0.Wf[0][2] = Wf[2];
    G0.b0[0] = bn0_aa; G0.b1[0] = bn0_ba; G0.outp[0] = xa1; G0.nmats[0] = 3;
    G0.A[1][0] = mean_ab; G0.Wf[1][0] = Wf[3];
    G0.A[1][1] = xb_bf;   G0.Wf[1][1] = Wf[4];
    G0.A[1][2] = nullptr; G0.Wf[1][2] = nullptr;
    G0.b0[1] = bn0_ab; G0.b1[1] = nullptr; G0.outp[1] = xb1; G0.nmats[1] = 2;
    gemm_mfma_multi_k<<<2 * GEMM_BLK, 256, 0, stream>>>(G0);

    // ---- layer 1: 2 aggregations fused (out_b unused downstream -> skipped) ----
    AggJobs A1;
    A1.xs[0] = xa1; A1.offs[0] = offs_aa; A1.ss[0] = ss_aa; A1.mean[0] = mean_aa;
    A1.xs[1] = xb1; A1.offs[1] = offs_ba; A1.ss[1] = ss_ba; A1.mean[1] = mean_ba;
    A1.xs[2] = xa1; A1.offs[2] = offs_aa; A1.ss[2] = ss_aa; A1.mean[2] = mean_aa; // unused
    aggregate_multi_k<<<2 * AGGBLK, 256, 0, stream>>>(A1);

    // ---- layer 1 GEMM ----
    GemmJobs G1;
    G1.A[0][0] = mean_aa; G1.Wf[0][0] = Wf[5];
    G1.A[0][1] = mean_ba; G1.Wf[0][1] = Wf[6];
    G1.A[0][2] = xa1;     G1.Wf[0][2] = Wf[7];
    G1.b0[0] = bn1_aa; G1.b1[0] = bn1_ba; G1.outp[0] = xa2; G1.nmats[0] = 3;
    G1.A[1][0] = nullptr; G1.Wf[1][0] = nullptr;
    G1.A[1][1] = nullptr; G1.Wf[1][1] = nullptr;
    G1.A[1][2] = nullptr; G1.Wf[1][2] = nullptr;
    G1.b0[1] = nullptr; G1.b1[1] = nullptr; G1.outp[1] = nullptr; G1.nmats[1] = 0;
    gemm_mfma_multi_k<<<GEMM_BLK, 256, 0, stream>>>(G1);

    // ---- pool + head ----
    pool_partial_k<<<(NA_N + 127) / 128, 256, 0, stream>>>(xa2, batch, pooled);
    out_head_k<<<1, 640, 0, stream>>>(pooled, bound, W_out, b_out, out);
}

// Round 13
// 423.674 us; speedup vs baseline: 3.8495x; 1.0437x over previous
//
#include <hip/hip_runtime.h>

#define NA_N 50000
#define NB_N 50000
#define NE   1000000
#define DF   128
#define NG_N 64
#define NC_N 10

// bucketed counting sort params
#define BSHIFT 7
#define BNODES 128
#define NBUK   391
#define BCAP   3584                      // fixed bucket capacity: mean 2560, sigma~50 -> 20 sigma
#define CHB    4096
#define NIT    (CHB / 256)
#define BINBLK ((NE + CHB - 1) / CHB)    // 245
#define AGGBLK ((NA_N * 64) / 256)       // 12500 blocks per aggregation job

#define CN4A (NA_N * DF / 4)
#define CN4T ((NA_N + NB_N) * DF / 4)
#define WELEMS (8 * 16384)
#define PZ4 (NG_N * DF / 4)
#define GZN (3 * NBUK)
#define PREP_ITEMS (CN4T + WELEMS + PZ4 + NA_N + GZN)
#define PREP_BLKS ((PREP_ITEMS + 255) / 256)

typedef __attribute__((ext_vector_type(8))) short short8;
typedef __attribute__((ext_vector_type(4))) float float4v;
typedef __attribute__((ext_vector_type(2))) float v2f;

__device__ __forceinline__ unsigned short f2bf(float f) {
    unsigned u = __float_as_uint(f);
    unsigned r = (u + 0x7fff + ((u >> 16) & 1)) >> 16;   // RNE
    return (unsigned short)r;
}
__device__ __forceinline__ float bf_lo(unsigned d) { return __uint_as_float(d << 16); }
__device__ __forceinline__ float bf_hi(unsigned d) { return __uint_as_float(d & 0xffff0000u); }
__device__ __forceinline__ v2f bfpair(unsigned d) { return (v2f){bf_lo(d), bf_hi(d)}; }
__device__ __forceinline__ unsigned packbf(float lo, float hi) {
    return (unsigned)f2bf(lo) | ((unsigned)f2bf(hi) << 16);
}

struct WJobs {
    const float* a[8];
    const float* b[8];
    unsigned short* d[8];
};

struct CsrJobs {
    const int* src[3];
    const int* dst[3];
    int* offs[3];
    int* ss[3];
    unsigned* ebuf[3];   // fixed-capacity bucket regions: bucket b at b*BCAP
};

// ---------------- prep: convert + weights + pooled zero + graph bounds + gcnt zero ----------------
// (R11 lesson: no device-fence tickets; launch boundaries are the cheap fences.)

__global__ __launch_bounds__(256) void prep_k(
        const float* __restrict__ xa, const float* __restrict__ xb,
        unsigned short* __restrict__ ya, unsigned short* __restrict__ yb,
        WJobs WJ, float* __restrict__ pooled,
        const int* __restrict__ batch, int* __restrict__ bound,
        int* __restrict__ gcnt3) {
    int i = blockIdx.x * 256 + threadIdx.x;
    if (i < CN4T) {
        const float* x = (i < CN4A) ? xa : xb;
        unsigned short* y = (i < CN4A) ? ya : yb;
        int j = (i < CN4A) ? i : i - CN4A;
        float4 v = ((const float4*)x)[j];
        uint2 o;
        o.x = packbf(v.x, v.y);
        o.y = packbf(v.z, v.w);
        ((uint2*)y)[j] = o;
    } else if (i < CN4T + WELEMS) {
        int t = i - CN4T;
        int which = t >> 14;
        t &= 16383;
        int j = t & 7, lane = (t >> 3) & 63, k0i = (t >> 9) & 3, n0 = t >> 11;
        int k = k0i * 32 + (lane >> 4) * 8 + j;
        int n = n0 * 16 + (lane & 15);
        float v = WJ.a[which][k * DF + n];
        if (WJ.b[which]) v += WJ.b[which][k * DF + n];
        WJ.d[which][t] = f2bf(v);
    } else if (i < CN4T + WELEMS + PZ4) {
        int t = i - CN4T - WELEMS;
        ((float4*)pooled)[t] = (float4){0.f, 0.f, 0.f, 0.f};
    } else if (i < CN4T + WELEMS + PZ4 + NA_N) {
        // graph boundary precompute over sorted batch
        int rr = i - (CN4T + WELEMS + PZ4);
        int c = batch[rr];
        if (rr == 0) {
            for (int g = 0; g <= c; g++) bound[g] = 0;
        } else {
            int p = batch[rr - 1];
            for (int g = p + 1; g <= c; g++) bound[g] = rr;
        }
        if (rr == NA_N - 1) {
            for (int g = c + 1; g <= NG_N; g++) bound[g] = NA_N;
        }
    } else if (i < PREP_ITEMS) {
        gcnt3[i - (CN4T + WELEMS + PZ4 + NA_N)] = 0;   // bucket counters (bin3 runs after)
    }
}

// ---------------- CSR build: bin (fixed-capacity reservation) / sort (self-computed bases) ----------------

__global__ __launch_bounds__(256) void bucket_bin3_k(CsrJobs J, int* __restrict__ gcnt3) {
    int which = blockIdx.x / BINBLK;
    int blk = blockIdx.x % BINBLK;
    const int* src = J.src[which];
    const int* dst = J.dst[which];
    int* gcnt = gcnt3 + which * NBUK;
    unsigned* ebuf = J.ebuf[which];
    __shared__ int cnt[NBUK];
    __shared__ int chunk[NBUK];
    for (int i = threadIdx.x; i < NBUK; i += 256) cnt[i] = 0;
    __syncthreads();
    int base = blk * CHB;
    int bk[NIT], rk[NIT];
    unsigned sv[NIT];
#pragma unroll
    for (int it = 0; it < NIT; it++) {
        int i = base + it * 256 + threadIdx.x;
        if (i < NE) {
            int d = dst[i];
            int b = d >> BSHIFT;
            bk[it] = b;
            rk[it] = atomicAdd(&cnt[b], 1);
            sv[it] = (unsigned)src[i] | ((unsigned)(d & (BNODES - 1)) << 24);
        } else {
            bk[it] = -1;
        }
    }
    __syncthreads();
    for (int i = threadIdx.x; i < NBUK; i += 256)
        chunk[i] = cnt[i] ? atomicAdd(&gcnt[i], cnt[i]) : 0;
    __syncthreads();
#pragma unroll
    for (int it = 0; it < NIT; it++) {
        if (bk[it] >= 0) {
            int p = chunk[bk[it]] + rk[it];
            if (p < BCAP)    // 20-sigma safety clamp (never hit in practice)
                ebuf[(size_t)bk[it] * BCAP + p] = sv[it];
        }
    }
}

__global__ __launch_bounds__(256) void bucket_sort3_k(CsrJobs J, const int* __restrict__ gcnt3,
                                                      int ndst) {
    __shared__ int hist[BNODES];
    __shared__ int loffs[BNODES];
    __shared__ int red1[256];
    __shared__ int red2[256];
    int which = blockIdx.x / NBUK;
    int b = blockIdx.x % NBUK;
    const unsigned* ebuf = J.ebuf[which] + (size_t)b * BCAP;
    const int* gc = gcnt3 + which * NBUK;
    int* offs = J.offs[which];
    int* ss = J.ss[which];
    int t = threadIdx.x;

    // compute ebase = sum of bucket counts before b, and total (for offs[ndst])
    int pb = 0, pa = 0;
    for (int i = t; i < NBUK; i += 256) {
        int v = gc[i];
        pa += v;
        if (i < b) pb += v;
    }
    red1[t] = pb;
    red2[t] = pa;
    __syncthreads();
    for (int d = 128; d > 0; d >>= 1) {
        if (t < d) { red1[t] += red1[t + d]; red2[t] += red2[t + d]; }
        __syncthreads();
    }
    int ebase = red1[0];
    int total = red2[0];
    int ecnt = gc[b];
    if (ecnt > BCAP) ecnt = BCAP;

    if (t < BNODES) hist[t] = 0;
    __syncthreads();
    for (int e = t; e < ecnt; e += 256)
        atomicAdd(&hist[ebuf[e] >> 24], 1);
    __syncthreads();
    if (t < BNODES) loffs[t] = hist[t];
    __syncthreads();
    for (int d = 1; d < BNODES; d <<= 1) {
        int x = 0;
        if (t < BNODES && t >= d) x = loffs[t - d];
        __syncthreads();
        if (t < BNODES && t >= d) loffs[t] += x;
        __syncthreads();
    }
    if (t < BNODES) {
        int ex = loffs[t] - hist[t];
        loffs[t] = ex;
        int gnode = b * BNODES + t;
        if (gnode < ndst) offs[gnode] = ebase + ex;
        hist[t] = 0;
    }
    if (b == 0 && t == 0) offs[ndst] = total;
    __syncthreads();
    for (int e = t; e < ecnt; e += 256) {
        unsigned w = ebuf[e];
        int dl = w >> 24;
        int r = atomicAdd(&hist[dl], 1);
        ss[ebase + loffs[dl] + r] = (int)(w & 0xFFFFFF);
    }
}

// ---------------- segment mean (at its structural floor: ~281 MB L2-fill / dispatch) ----------------

struct AggJobs {
    const unsigned short* xs[3];
    const int* offs[3];
    const int* ss[3];
    unsigned short* mean[3];
};

__device__ __forceinline__ void acc_u4(uint4 u, v2f acc[4]) {
    acc[0] += bfpair(u.x);
    acc[1] += bfpair(u.y);
    acc[2] += bfpair(u.z);
    acc[3] += bfpair(u.w);
}

__global__ __launch_bounds__(256) void aggregate_multi_k(AggJobs J) {
    int job = blockIdx.x / AGGBLK;
    int blk = blockIdx.x % AGGBLK;
    int node = (blk * 256 + threadIdx.x) >> 6;
    int lane = threadIdx.x & 63;
    const unsigned* xs = (const unsigned*)J.xs[job];
    const int* offs = J.offs[job];
    const int* ss = J.ss[job];
    int o0 = offs[node], o1 = offs[node + 1];
    int deg = o1 - o0;
    int idx = (lane < deg) ? ss[o0 + lane] : 0;
    int sub = lane >> 4;
    int q4 = (lane & 15) * 4;
    const unsigned* xq = xs + q4;
    v2f acc[4];
#pragma unroll
    for (int k = 0; k < 4; k++) acc[k] = (v2f){0.f, 0.f};

    int dcap = deg < 64 ? deg : 64;
    int e0 = sub;
    if (dcap <= 32) {
        int s0 = __shfl(idx, e0, 64);
        int s1 = __shfl(idx, e0 + 4, 64);
        int s2 = __shfl(idx, e0 + 8, 64);
        int s3 = __shfl(idx, e0 + 12, 64);
        int s4 = __shfl(idx, e0 + 16, 64);
        int s5 = __shfl(idx, e0 + 20, 64);
        int s6 = __shfl(idx, e0 + 24, 64);
        int s7 = __shfl(idx, e0 + 28, 64);
        uint4 u0 = *(const uint4*)(xq + (size_t)s0 * 64);
        uint4 u1 = *(const uint4*)(xq + (size_t)s1 * 64);
        uint4 u2 = *(const uint4*)(xq + (size_t)s2 * 64);
        uint4 u3 = *(const uint4*)(xq + (size_t)s3 * 64);
        if (dcap > 16) {
            uint4 u4 = *(const uint4*)(xq + (size_t)s4 * 64);
            uint4 u5 = *(const uint4*)(xq + (size_t)s5 * 64);
            uint4 u6 = *(const uint4*)(xq + (size_t)s6 * 64);
            uint4 u7 = *(const uint4*)(xq + (size_t)s7 * 64);
            acc_u4(u0, acc);
            acc_u4(u1, acc);
            acc_u4(u2, acc);
            acc_u4(u3, acc);
            if (e0 + 16 < dcap) acc_u4(u4, acc);
            if (e0 + 20 < dcap) acc_u4(u5, acc);
            if (e0 + 24 < dcap) acc_u4(u6, acc);
            if (e0 + 28 < dcap) acc_u4(u7, acc);
        } else {
            if (e0 < dcap)      acc_u4(u0, acc);
            if (e0 + 4 < dcap)  acc_u4(u1, acc);
            if (e0 + 8 < dcap)  acc_u4(u2, acc);
            if (e0 + 12 < dcap) acc_u4(u3, acc);
        }
    } else {
        int full = dcap & ~15;
        int b0 = 0;
        for (; b0 < full; b0 += 16) {
            int ee = b0 + sub;
            int s0 = __shfl(idx, ee, 64);
            int s1 = __shfl(idx, ee + 4, 64);
            int s2 = __shfl(idx, ee + 8, 64);
            int s3 = __shfl(idx, ee + 12, 64);
            uint4 u0 = *(const uint4*)(xq + (size_t)s0 * 64);
            uint4 u1 = *(const uint4*)(xq + (size_t)s1 * 64);
            uint4 u2 = *(const uint4*)(xq + (size_t)s2 * 64);
            uint4 u3 = *(const uint4*)(xq + (size_t)s3 * 64);
            acc_u4(u0, acc);
            acc_u4(u1, acc);
            acc_u4(u2, acc);
            acc_u4(u3, acc);
        }
        if (b0 < dcap) {
            int ee = b0 + sub;
            int s0 = __shfl(idx, ee, 64);
            int s1 = __shfl(idx, ee + 4, 64);
            int s2 = __shfl(idx, ee + 8, 64);
            int s3 = __shfl(idx, ee + 12, 64);
            uint4 u0 = *(const uint4*)(xq + (size_t)s0 * 64);
            uint4 u1 = *(const uint4*)(xq + (size_t)s1 * 64);
            uint4 u2 = *(const uint4*)(xq + (size_t)s2 * 64);
            uint4 u3 = *(const uint4*)(xq + (size_t)s3 * 64);
            if (ee < dcap)      acc_u4(u0, acc);
            if (ee + 4 < dcap)  acc_u4(u1, acc);
            if (ee + 8 < dcap)  acc_u4(u2, acc);
            if (ee + 12 < dcap) acc_u4(u3, acc);
        }
        for (int e2 = 64 + sub; e2 < deg; e2 += 4) {
            int s = ss[o0 + e2];
            uint4 u = *(const uint4*)(xq + (size_t)s * 64);
            acc_u4(u, acc);
        }
    }

#pragma unroll
    for (int k = 0; k < 4; k++) {
        acc[k].x += __shfl_down(acc[k].x, 32, 64);
        acc[k].y += __shfl_down(acc[k].y, 32, 64);
        acc[k].x += __shfl_down(acc[k].x, 16, 64);
        acc[k].y += __shfl_down(acc[k].y, 16, 64);
    }
    if (sub == 0) {
        float inv = 1.0f / (float)(deg > 0 ? deg : 1);
        uint4 o;
        o.x = packbf(acc[0].x * inv, acc[0].y * inv);
        o.y = packbf(acc[1].x * inv, acc[1].y * inv);
        o.z = packbf(acc[2].x * inv, acc[2].y * inv);
        o.w = packbf(acc[3].x * inv, acc[3].y * inv);
        *(uint4*)((unsigned*)J.mean[job] + (size_t)node * 64 + q4) = o;
    }
}

// ---------------- bf16 MFMA GEMM, up to 2 jobs per launch, Wf staged in LDS ----------------

struct GemmJobs {
    const unsigned short* A[2][3];
    const unsigned short* Wf[2][3];
    const float* b0[2];
    const float* b1[2];
    unsigned short* outp[2];
    int nmats[2];
};

#define GEMM_BLK ((NA_N + 127) / 128)    // 391 (NA_N == NB_N)

__global__ __launch_bounds__(256) void gemm_mfma_multi_k(GemmJobs J) {
    __shared__ unsigned short Wfs[16384];   // 32 KB: one mat's fragments
    int job = blockIdx.x / GEMM_BLK;
    int blk = blockIdx.x % GEMM_BLK;
    const int nrows = NA_N;
    int lane = threadIdx.x & 63;
    int wv = threadIdx.x >> 6;
    int r0 = blk * 128 + wv * 32;
    int m = lane & 15, quad = lane >> 4;
    int rowA = r0 + m;      if (rowA >= nrows) rowA = nrows - 1;
    int rowB = r0 + 16 + m; if (rowB >= nrows) rowB = nrows - 1;
    int nmats = J.nmats[job];

    float4v acc0[8], acc1[8];
#pragma unroll
    for (int n0 = 0; n0 < 8; n0++) {
        acc0[n0] = (float4v){0.f, 0.f, 0.f, 0.f};
        acc1[n0] = (float4v){0.f, 0.f, 0.f, 0.f};
    }

    for (int mat = 0; mat < nmats; mat++) {
        const unsigned short* A  = J.A[job][mat];
        __syncthreads();
        {
            const uint4* src = (const uint4*)J.Wf[job][mat];
            uint4* dstl = (uint4*)Wfs;
#pragma unroll
            for (int i = 0; i < 8; i++)
                dstl[threadIdx.x * 8 + i] = src[threadIdx.x * 8 + i];
        }
        __syncthreads();
#pragma unroll
        for (int k0i = 0; k0i < 4; k0i++) {
            short8 a0 = *(const short8*)(A + (size_t)rowA * DF + k0i * 32 + quad * 8);
            short8 a1 = *(const short8*)(A + (size_t)rowB * DF + k0i * 32 + quad * 8);
#pragma unroll
            for (int n0 = 0; n0 < 8; n0++) {
                short8 b = *(const short8*)(Wfs + (((n0 * 4 + k0i) * 64 + lane) << 3));
                acc0[n0] = __builtin_amdgcn_mfma_f32_16x16x32_bf16(a0, b, acc0[n0], 0, 0, 0);
                acc1[n0] = __builtin_amdgcn_mfma_f32_16x16x32_bf16(a1, b, acc1[n0], 0, 0, 0);
            }
        }
    }

    const float* b0 = J.b0[job];
    const float* b1 = J.b1[job];
    unsigned short* out = J.outp[job];
#pragma unroll
    for (int n0 = 0; n0 < 8; n0++) {
        int c = n0 * 16 + m;
        float bb = b0[c] + (b1 ? b1[c] : 0.f);
#pragma unroll
        for (int i = 0; i < 4; i++) {
            int r = r0 + quad * 4 + i;
            if (r < nrows) out[(size_t)r * DF + c] = f2bf(fmaxf(acc0[n0][i] + bb, 0.f));
            int r2 = r0 + 16 + quad * 4 + i;
            if (r2 < nrows) out[(size_t)r2 * DF + c] = f2bf(fmaxf(acc1[n0][i] + bb, 0.f));
        }
    }
}

// ---------------- pooling + head (separate launches; launch boundary = cheap fence) ----------------

__global__ __launch_bounds__(256) void pool_partial_k(
    const unsigned short* __restrict__ xa, const int* __restrict__ batch,
    float* __restrict__ pooled) {
    int c2 = threadIdx.x & 63;
    int way = threadIdx.x >> 6;
    int row0 = blockIdx.x * 128;
    int rend = row0 + 128;
    if (rend > NA_N) rend = NA_N;
    const unsigned* x = (const unsigned*)xa;
    float2 acc = {0.f, 0.f};
    int cur_g = -1;
    for (int r = row0 + way; r < rend; r += 4) {
        int g = batch[r];
        if (g != cur_g) {
            if (cur_g >= 0) {
                atomicAdd(&pooled[cur_g * DF + c2 * 2], acc.x);
                atomicAdd(&pooled[cur_g * DF + c2 * 2 + 1], acc.y);
            }
            cur_g = g;
            acc = (float2){0.f, 0.f};
        }
        unsigned d = x[(size_t)r * 64 + c2];
        acc.x += bf_lo(d);
        acc.y += bf_hi(d);
    }
    if (cur_g >= 0) {
        atomicAdd(&pooled[cur_g * DF + c2 * 2], acc.x);
        atomicAdd(&pooled[cur_g * DF + c2 * 2 + 1], acc.y);
    }
}

__global__ void out_head_k(const float* __restrict__ pooled, const int* __restrict__ bound,
                           const float* __restrict__ Wout, const float* __restrict__ bout,
                           float* __restrict__ out) {
    int tid = threadIdx.x;
    if (tid >= NG_N * NC_N) return;
    int g = tid / NC_N, c = tid % NC_N;
    int lo = bound[g], hi = bound[g + 1];
    int cnt = hi - lo;
    float inv = 1.0f / (float)(cnt > 0 ? cnt : 1);
    float s = 0.f;
    for (int k = 0; k < DF; k++) s += pooled[g * DF + k] * Wout[k * NC_N + c];
    out[tid] = s * inv + bout[c];
}

// ---------------- launcher ----------------

extern "C" void kernel_launch(void* const* d_in, const int* in_sizes, int n_in,
                              void* d_out, int out_size, void* d_ws, size_t ws_size,
                              hipStream_t stream) {
    const float* x_a = (const float*)d_in[0];
    const float* x_b = (const float*)d_in[1];
    const int* ei_aa = (const int*)d_in[2];
    const int* ei_ab = (const int*)d_in[3];
    const int* ei_ba = (const int*)d_in[4];
    const int* batch = (const int*)d_in[5];
    const float *Wn0_aa = (const float*)d_in[6],  *bn0_aa = (const float*)d_in[7],  *Wr0_aa = (const float*)d_in[8];
    const float *Wn0_ab = (const float*)d_in[9],  *bn0_ab = (const float*)d_in[10], *Wr0_ab = (const float*)d_in[11];
    const float *Wn0_ba = (const float*)d_in[12], *bn0_ba = (const float*)d_in[13], *Wr0_ba = (const float*)d_in[14];
    const float *Wn1_aa = (const float*)d_in[15], *bn1_aa = (const float*)d_in[16], *Wr1_aa = (const float*)d_in[17];
    // d_in[18..20] unused (layer-2 out_b never consumed)
    const float *Wn1_ba = (const float*)d_in[21], *bn1_ba = (const float*)d_in[22], *Wr1_ba = (const float*)d_in[23];
    const float *W_out = (const float*)d_in[24], *b_out = (const float*)d_in[25];
    float* out = (float*)d_out;

    char* w = (char*)d_ws;
    size_t off = 0;
    auto alloc = [&](size_t b) -> char* {
        char* p = w + off;
        off += (b + 255) & ~(size_t)255;
        return p;
    };

    int* offs_aa = (int*)alloc((NA_N + 1) * 4);
    int* ss_aa   = (int*)alloc((size_t)NE * 4);
    int* offs_ba = (int*)alloc((NA_N + 1) * 4);
    int* ss_ba   = (int*)alloc((size_t)NE * 4);
    int* offs_ab = (int*)alloc((NB_N + 1) * 4);
    int* ss_ab   = (int*)alloc((size_t)NE * 4);
    int* gcnt3  = (int*)alloc(3 * NBUK * 4);
    unsigned* ebuf0 = (unsigned*)alloc((size_t)NBUK * BCAP * 4);
    unsigned* ebuf1 = (unsigned*)alloc((size_t)NBUK * BCAP * 4);
    unsigned* ebuf2 = (unsigned*)alloc((size_t)NBUK * BCAP * 4);

    unsigned short* xa_bf   = (unsigned short*)alloc((size_t)NA_N * DF * 2);
    unsigned short* xb_bf   = (unsigned short*)alloc((size_t)NB_N * DF * 2);
    unsigned short* mean_aa = (unsigned short*)alloc((size_t)NA_N * DF * 2);
    unsigned short* mean_ba = (unsigned short*)alloc((size_t)NA_N * DF * 2);
    unsigned short* mean_ab = (unsigned short*)alloc((size_t)NB_N * DF * 2);
    unsigned short* xa1 = (unsigned short*)alloc((size_t)NA_N * DF * 2);
    unsigned short* xb1 = (unsigned short*)alloc((size_t)NB_N * DF * 2);
    unsigned short* xa2 = mean_ab;  // alias: mean_ab dead once layer-0 dst-b GEMM ran
    unsigned short* Wf[8];
    for (int i = 0; i < 8; i++) Wf[i] = (unsigned short*)alloc((size_t)DF * DF * 2);
    float* pooled = (float*)alloc(NG_N * DF * 4);
    int* bound = (int*)alloc((NG_N + 1) * 4);

    // ---- CSR jobs ----
    CsrJobs CJ;
    CJ.src[0] = ei_aa;      CJ.dst[0] = ei_aa + NE;
    CJ.src[1] = ei_ba;      CJ.dst[1] = ei_ba + NE;
    CJ.src[2] = ei_ab;      CJ.dst[2] = ei_ab + NE;
    CJ.offs[0] = offs_aa;   CJ.ss[0] = ss_aa;   CJ.ebuf[0] = ebuf0;
    CJ.offs[1] = offs_ba;   CJ.ss[1] = ss_ba;   CJ.ebuf[1] = ebuf1;
    CJ.offs[2] = offs_ab;   CJ.ss[2] = ss_ab;   CJ.ebuf[2] = ebuf2;

    WJobs WJ;
    WJ.a[0] = Wn0_aa; WJ.b[0] = nullptr; WJ.d[0] = Wf[0];
    WJ.a[1] = Wn0_ba; WJ.b[1] = nullptr; WJ.d[1] = Wf[1];
    WJ.a[2] = Wr0_aa; WJ.b[2] = Wr0_ba;  WJ.d[2] = Wf[2];
    WJ.a[3] = Wn0_ab; WJ.b[3] = nullptr; WJ.d[3] = Wf[3];
    WJ.a[4] = Wr0_ab; WJ.b[4] = nullptr; WJ.d[4] = Wf[4];
    WJ.a[5] = Wn1_aa; WJ.b[5] = nullptr; WJ.d[5] = Wf[5];
    WJ.a[6] = Wn1_ba; WJ.b[6] = nullptr; WJ.d[6] = Wf[6];
    WJ.a[7] = Wr1_aa; WJ.b[7] = Wr1_ba;  WJ.d[7] = Wf[7];

    // ---- prep (includes gcnt zeroing), then bin/sort (no hist, no scan, no memset) ----
    prep_k<<<PREP_BLKS, 256, 0, stream>>>(
        x_a, x_b, xa_bf, xb_bf, WJ, pooled, batch, bound, gcnt3);
    bucket_bin3_k<<<3 * BINBLK, 256, 0, stream>>>(CJ, gcnt3);
    bucket_sort3_k<<<3 * NBUK, 256, 0, stream>>>(CJ, gcnt3, NA_N);

    // ---- layer 0: 3 aggregations fused ----
    AggJobs A0;
    A0.xs[0] = xa_bf; A0.offs[0] = offs_aa; A0.ss[0] = ss_aa; A0.mean[0] = mean_aa;
    A0.xs[1] = xb_bf; A0.offs[1] = offs_ba; A0.ss[1] = ss_ba; A0.mean[1] = mean_ba;
    A0.xs[2] = xa_bf; A0.offs[2] = offs_ab; A0.ss[2] = ss_ab; A0.mean[2] = mean_ab;
    aggregate_multi_k<<<3 * AGGBLK, 256, 0, stream>>>(A0);

    // ---- layer 0: both GEMMs in one launch ----
    GemmJobs G0;
    G0.A[0][0] = mean_aa; G0.Wf[0][0] = Wf[0];
    G0.A[0][1] = mean_ba; G0.Wf[0][1] = Wf[1];
    G0.A[0][2] = xa_bf;   G0.Wf[0][2] = Wf[2];
    G0.b0[0] = bn0_aa; G0.b1[0] = bn0_ba; G0.outp[0] = xa1; G0.nmats[0] = 3;
    G0.A[1][0] = mean_ab; G0.Wf[1][0] = Wf[3];
    G0.A[1][1] = xb_bf;   G0.Wf[1][1] = Wf[4];
    G0.A[1][2] = nullptr; G0.Wf[1][2] = nullptr;
    G0.b0[1] = bn0_ab; G0.b1[1] = nullptr; G0.outp[1] = xb1; G0.nmats[1] = 2;
    gemm_mfma_multi_k<<<2 * GEMM_BLK, 256, 0, stream>>>(G0);

    // ---- layer 1: 2 aggregations fused (out_b unused downstream -> skipped) ----
    AggJobs A1;
    A1.xs[0] = xa1; A1.offs[0] = offs_aa; A1.ss[0] = ss_aa; A1.mean[0] = mean_aa;
    A1.xs[1] = xb1; A1.offs[1] = offs_ba; A1.ss[1] = ss_ba; A1.mean[1] = mean_ba;
    A1.xs[2] = xa1; A1.offs[2] = offs_aa; A1.ss[2] = ss_aa; A1.mean[2] = mean_aa; // unused
    aggregate_multi_k<<<2 * AGGBLK, 256, 0, stream>>>(A1);

    // ---- layer 1 GEMM ----
    GemmJobs G1;
    G1.A[0][0] = mean_aa; G1.Wf[0][0] = Wf[5];
    G1.A[0][1] = mean_ba; G1.Wf[0][1] = Wf[6];
    G1.A[0][2] = xa1;     G1.Wf[0][2] = Wf[7];
    G1.b0[0] = bn1_aa; G1.b1[0] = bn1_ba; G1.outp[0] = xa2; G1.nmats[0] = 3;
    G1.A[1][0] = nullptr; G1.Wf[1][0] = nullptr;
    G1.A[1][1] = nullptr; G1.Wf[1][1] = nullptr;
    G1.A[1][2] = nullptr; G1.Wf[1][2] = nullptr;
    G1.b0[1] = nullptr; G1.b1[1] = nullptr; G1.outp[1] = nullptr; G1.nmats[1] = 0;
    gemm_mfma_multi_k<<<GEMM_BLK, 256, 0, stream>>>(G1);

    // ---- pool + head ----
    pool_partial_k<<<(NA_N + 127) / 128, 256, 0, stream>>>(xa2, batch, pooled);
    out_head_k<<<1, 640, 0, stream>>>(pooled, bound, W_out, b_out, out);
}